// Round 2
// baseline (724.452 us; speedup 1.0000x reference)
//
#include <hip/hip_runtime.h>

constexpr int BB = 8;
constexpr int HH = 1024;
constexpr int WW = 1024;
constexpr int HW = HH * WW;
constexpr int TOTAL = BB * HW;

constexpr float RADIUS = 15.0f;
constexpr float THR_VOTES = 0.01f;
constexpr float THR_PEAKS = 0.2f;
constexpr int RV = 7;  // 15x15 box-sum radius
constexpr int RP = 8;  // 17x17 max-pool radius
// pi * 15^2 in double, rounded to f32 (matches jnp: votes / (np.pi*R*R))
constexpr float DIVISOR = 706.8583470577035f;

__global__ void scatter_votes(const float* __restrict__ kp,
                              const float* __restrict__ off,
                              float* __restrict__ votes) {
    int i = blockIdx.x * blockDim.x + threadIdx.x;
    if (i >= TOTAL) return;
    int b = i >> 20;           // / HW
    int p = i & (HW - 1);
    int y = p >> 10;
    int x = p & (WW - 1);
    float w  = kp[i];
    float ox = off[b * 2 * HW + p];
    float oy = off[b * 2 * HW + HW + p];
    // forbid FMA contraction: must match numpy's mul-then-add rounding exactly,
    // else a .5-boundary vote lands in the adjacent cell.
    float fx = __fadd_rn((float)x, __fmul_rn(RADIUS, ox));
    float fy = __fadd_rn((float)y, __fmul_rn(RADIUS, oy));
    int vx = (int)rintf(fx);   // round-half-even == jnp.round
    int vy = (int)rintf(fy);
    if (vx >= 0 && vx < WW && vy >= 0 && vy < HH && w >= THR_VOTES) {
        atomicAdd(&votes[b * HW + vy * WW + vx], w);
    }
}

__global__ void row_boxsum(const float* __restrict__ in, float* __restrict__ out) {
    int i = blockIdx.x * blockDim.x + threadIdx.x;
    if (i >= TOTAL) return;
    int x = i & (WW - 1);
    int rowbase = i - x;
    float s = 0.0f;
#pragma unroll
    for (int dx = -RV; dx <= RV; ++dx) {
        int xx = x + dx;
        if (xx >= 0 && xx < WW) s += in[rowbase + xx];
    }
    out[i] = s / DIVISOR;      // scale folded in once (commutes with the sums)
}

__global__ void col_boxsum(const float* __restrict__ in, float* __restrict__ out) {
    int i = blockIdx.x * blockDim.x + threadIdx.x;
    if (i >= TOTAL) return;
    int p = i & (HW - 1);
    int y = p >> 10;
    float s = 0.0f;
#pragma unroll
    for (int dy = -RV; dy <= RV; ++dy) {
        int yy = y + dy;
        if (yy >= 0 && yy < HH) s += in[i + dy * WW];
    }
    out[i] = s;
}

__global__ void row_maxpool(const float* __restrict__ in, float* __restrict__ out) {
    int i = blockIdx.x * blockDim.x + threadIdx.x;
    if (i >= TOTAL) return;
    int x = i & (WW - 1);
    int rowbase = i - x;
    float m = -INFINITY;
#pragma unroll
    for (int dx = -RP; dx <= RP; ++dx) {
        int xx = x + dx;
        if (xx >= 0 && xx < WW) m = fmaxf(m, in[rowbase + xx]);
    }
    out[i] = m;
}

// col max-pool fused with the peak decision: reads row-maxed W and votes V,
// writes peaks (0.0/1.0) directly. Saves one full 64MB pass + launch.
__global__ void col_maxpool_peaks(const float* __restrict__ in,
                                  const float* __restrict__ votes,
                                  float* __restrict__ peaks) {
    int i = blockIdx.x * blockDim.x + threadIdx.x;
    if (i >= TOTAL) return;
    int p = i & (HW - 1);
    int y = p >> 10;
    float m = -INFINITY;
#pragma unroll
    for (int dy = -RP; dy <= RP; ++dy) {
        int yy = y + dy;
        if (yy >= 0 && yy < HH) m = fmaxf(m, in[i + dy * WW]);
    }
    float v = votes[i];
    // np.isclose(votes, dilated): |a-b| <= atol + rtol*|b|, b = dilated
    bool close = fabsf(v - m) <= (1e-8f + 1e-5f * fabsf(m));
    peaks[i] = (close && v > THR_PEAKS) ? 1.0f : 0.0f;
}

extern "C" void kernel_launch(void* const* d_in, const int* in_sizes, int n_in,
                              void* d_out, int out_size, void* d_ws, size_t ws_size,
                              hipStream_t stream) {
    const float* kp  = (const float*)d_in[0];
    const float* off = (const float*)d_in[1];
    float* V = (float*)d_out;            // final votes (output 0), 8M floats
    float* P = (float*)d_out + TOTAL;    // peaks (output 1); scratch mid-pipeline
    float* W = (float*)d_ws;             // 32 MB scratch

    const int threads = 256;
    const int blocks = (TOTAL + threads - 1) / threads;

    hipMemsetAsync(W, 0, (size_t)TOTAL * sizeof(float), stream);
    scatter_votes<<<blocks, threads, 0, stream>>>(kp, off, W);
    row_boxsum  <<<blocks, threads, 0, stream>>>(W, P);
    col_boxsum  <<<blocks, threads, 0, stream>>>(P, V);   // final votes -> out[0]
    row_maxpool <<<blocks, threads, 0, stream>>>(V, W);   // row-maxed -> W
    col_maxpool_peaks<<<blocks, threads, 0, stream>>>(W, V, P);  // peaks -> out[1]
}

// Round 4
// 396.242 us; speedup vs baseline: 1.8283x; 1.8283x over previous
//
#include <hip/hip_runtime.h>

constexpr int BB = 8;
constexpr int HH = 1024;
constexpr int WW = 1024;
constexpr int HW = HH * WW;
constexpr int TOTAL = BB * HW;

constexpr float RADIUS = 15.0f;
constexpr float THR_VOTES = 0.01f;
constexpr float THR_PEAKS = 0.2f;
// pi * 15^2 in double, rounded to f32 (matches jnp: votes / (np.pi*R*R))
constexpr float DIVISOR = 706.8583470577035f;

constexpr int TS = 128;         // gather output tile
constexpr int AP = 48;          // apron: votes with |delta|<=48 are "near"
constexpr int RG = TS + 2 * AP; // 224 input region per tile
constexpr int FAR_CAP = (TOTAL - 16) / 2;

// ---------------------------------------------------------------------------
// Pass 1: gather votes. Each block owns a 128x128 tile of the votes image,
// scans the 224x224 source region, recomputes vote targets with the EXACT
// same arithmetic as the reference (mul/add no-FMA + rintf half-even), and
// accumulates near votes in LDS. Far votes (|delta|>48, ~0.27%) are appended
// to a compact list by the tile that owns the SOURCE pixel (each pixel in
// exactly one tile -> counted once). Tile written with plain stores.
// ---------------------------------------------------------------------------
__global__ __launch_bounds__(512)
void gather_votes(const float* __restrict__ kp, const float* __restrict__ off,
                  float* __restrict__ vraw, float* __restrict__ farbuf) {
    __shared__ float tile[TS * TS];   // 64 KB
    const int blk = blockIdx.x;       // 512 blocks = 8 batches * 64 tiles
    const int b   = blk >> 6;
    const int t   = blk & 63;
    const int ty0 = (t >> 3) * TS;
    const int tx0 = (t & 7) * TS;

    float4* tf4 = (float4*)tile;
    for (int j = threadIdx.x; j < TS * TS / 4; j += 512)
        tf4[j] = make_float4(0.f, 0.f, 0.f, 0.f);
    __syncthreads();

    const float* kpb  = kp  + (long)b * HW;
    const float* offx = off + (long)b * 2 * HW;
    const float* offy = offx + HW;
    int* cnt = (int*)farbuf;
    int* fidx = (int*)farbuf;

    for (int idx = threadIdx.x; idx < RG * RG; idx += 512) {
        const int py = ty0 - AP + idx / RG;
        const int px = tx0 - AP + idx % RG;
        if (px < 0 || px >= WW || py < 0 || py >= HH) continue;
        const int p = py * WW + px;
        const float w  = kpb[p];
        const float ox = offx[p];
        const float oy = offy[p];
        // forbid FMA contraction: must match numpy's mul-then-add rounding,
        // else a .5-boundary vote lands in the adjacent cell.
        const float fx = __fadd_rn((float)px, __fmul_rn(RADIUS, ox));
        const float fy = __fadd_rn((float)py, __fmul_rn(RADIUS, oy));
        const int vx = (int)rintf(fx);   // round-half-even == np.round
        const int vy = (int)rintf(fy);
        if (vx < 0 || vx >= WW || vy < 0 || vy >= HH || w < THR_VOTES) continue;
        const int dx = vx - px, dy = vy - py;
        if (dx >= -AP && dx <= AP && dy >= -AP && dy <= AP) {
            // near vote: if target in this tile, LDS-accumulate.
            const int lx = vx - tx0, ly = vy - ty0;
            if (lx >= 0 && lx < TS && ly >= 0 && ly < TS)
                atomicAdd(&tile[ly * TS + lx], w);
        } else if (px >= tx0 && px < tx0 + TS && py >= ty0 && py < ty0 + TS) {
            // far vote, owned by the source pixel's tile: append to list.
            const int slot = atomicAdd(cnt, 1);
            if (slot < FAR_CAP) {
                fidx[16 + 2 * slot]   = b * HW + vy * WW + vx;
                farbuf[17 + 2 * slot] = w;
            }
        }
    }
    __syncthreads();

    float* vb = vraw + (long)b * HW;
    for (int j = threadIdx.x; j < TS * TS / 4; j += 512) {
        const int r  = j / (TS / 4);
        const int c4 = j % (TS / 4);
        *(float4*)&vb[(ty0 + r) * WW + tx0 + c4 * 4] = tf4[j];
    }
}

// Pass 1b: flush the (tiny) far-vote list with global atomics.
__global__ void far_scatter(const float* __restrict__ farbuf,
                            float* __restrict__ vraw) {
    const int n = min(((const int*)farbuf)[0], FAR_CAP);
    const int stride = gridDim.x * blockDim.x;
    for (int i = blockIdx.x * blockDim.x + threadIdx.x; i < n; i += stride) {
        const int tg = ((const int*)farbuf)[16 + 2 * i];
        atomicAdd(&vraw[tg], farbuf[17 + 2 * i]);
    }
}

// ---------------------------------------------------------------------------
// Pass 2: 15x15 box-sum, separable, /DIVISOR folded into row pass.
// Each thread makes 4 horizontal outputs from 5 aligned float4 loads.
// ---------------------------------------------------------------------------
__global__ __launch_bounds__(256)
void box_row(const float* __restrict__ in, float* __restrict__ out) {
    const long base = (long)blockIdx.x * WW;   // one image row per block
    const int c0 = threadIdx.x * 4;
    float v[20];
#pragma unroll
    for (int k = 0; k < 5; ++k) {
        const int c = c0 - 8 + 4 * k;
        float4 f = (c >= 0 && c <= WW - 4) ? *(const float4*)&in[base + c]
                                           : make_float4(0.f, 0.f, 0.f, 0.f);
        v[4 * k + 0] = f.x; v[4 * k + 1] = f.y;
        v[4 * k + 2] = f.z; v[4 * k + 3] = f.w;
    }
    float s = 0.f;
#pragma unroll
    for (int k = 1; k <= 15; ++k) s += v[k];
    float4 o;
    o.x = s / DIVISOR;
    s += v[16] - v[1];  o.y = s / DIVISOR;
    s += v[17] - v[2];  o.z = s / DIVISOR;
    s += v[18] - v[3];  o.w = s / DIVISOR;
    *(float4*)&out[base + c0] = o;
}

// Each thread makes 4 vertical outputs (rows r0..r0+3) from 18 coalesced reads.
__global__ __launch_bounds__(256)
void box_col(const float* __restrict__ in, float* __restrict__ out) {
    const int bi = blockIdx.x;               // 8192 = 8 * 256 * 4
    const int xg = bi & 3;
    const int rg = (bi >> 2) & 255;
    const int b  = bi >> 10;
    const int x  = xg * 256 + threadIdx.x;
    const int r0 = rg * 4;
    const float* p = in + (long)b * HW + x;
    float v[18];
#pragma unroll
    for (int k = 0; k < 18; ++k) {
        const int r = r0 - 7 + k;
        v[k] = (r >= 0 && r < HH) ? p[(long)r * WW] : 0.f;
    }
    float s = 0.f;
#pragma unroll
    for (int k = 0; k < 15; ++k) s += v[k];
    float* q = out + (long)b * HW + x;
    q[(long)(r0 + 0) * WW] = s;
    s += v[15] - v[0]; q[(long)(r0 + 1) * WW] = s;
    s += v[16] - v[1]; q[(long)(r0 + 2) * WW] = s;
    s += v[17] - v[2]; q[(long)(r0 + 3) * WW] = s;
}

// ---------------------------------------------------------------------------
// Pass 3: 17x17 max-pool, separable; col pass fused with the peak decision.
// ---------------------------------------------------------------------------
__global__ __launch_bounds__(256)
void max_row(const float* __restrict__ in, float* __restrict__ out) {
    const long base = (long)blockIdx.x * WW;
    const int c0 = threadIdx.x * 4;
    float v[20];
#pragma unroll
    for (int k = 0; k < 5; ++k) {
        const int c = c0 - 8 + 4 * k;
        float4 f = (c >= 0 && c <= WW - 4)
                       ? *(const float4*)&in[base + c]
                       : make_float4(-INFINITY, -INFINITY, -INFINITY, -INFINITY);
        v[4 * k + 0] = f.x; v[4 * k + 1] = f.y;
        v[4 * k + 2] = f.z; v[4 * k + 3] = f.w;
    }
    float m = v[3];
#pragma unroll
    for (int k = 4; k <= 16; ++k) m = fmaxf(m, v[k]);   // common v[3..16]
    float4 o;
    o.x = fmaxf(fmaxf(m, v[0]),  fmaxf(v[1],  v[2]));
    o.y = fmaxf(fmaxf(m, v[1]),  fmaxf(v[2],  v[17]));
    o.z = fmaxf(fmaxf(m, v[2]),  fmaxf(v[17], v[18]));
    o.w = fmaxf(fmaxf(m, v[17]), fmaxf(v[18], v[19]));
    *(float4*)&out[base + c0] = o;
}

__global__ __launch_bounds__(256)
void max_col_peaks(const float* __restrict__ rowmaxed,
                   const float* __restrict__ votes,
                   float* __restrict__ peaks) {
    const int bi = blockIdx.x;
    const int xg = bi & 3;
    const int rg = (bi >> 2) & 255;
    const int b  = bi >> 10;
    const int x  = xg * 256 + threadIdx.x;
    const int r0 = rg * 4;
    const float* p = rowmaxed + (long)b * HW + x;
    float v[20];
#pragma unroll
    for (int k = 0; k < 20; ++k) {
        const int r = r0 - 8 + k;
        v[k] = (r >= 0 && r < HH) ? p[(long)r * WW] : -INFINITY;
    }
    float m = v[3];
#pragma unroll
    for (int k = 4; k <= 16; ++k) m = fmaxf(m, v[k]);   // common rows
    float d[4];
    d[0] = fmaxf(fmaxf(m, v[0]),  fmaxf(v[1],  v[2]));
    d[1] = fmaxf(fmaxf(m, v[1]),  fmaxf(v[2],  v[17]));
    d[2] = fmaxf(fmaxf(m, v[2]),  fmaxf(v[17], v[18]));
    d[3] = fmaxf(fmaxf(m, v[17]), fmaxf(v[18], v[19]));

    const float* vp = votes + (long)b * HW + x;
    float* q = peaks + (long)b * HW + x;
#pragma unroll
    for (int j = 0; j < 4; ++j) {
        const float vv = vp[(long)(r0 + j) * WW];
        // np.isclose(votes, dilated): |a-b| <= atol + rtol*|b|, b = dilated
        const bool close = fabsf(vv - d[j]) <= (1e-8f + 1e-5f * fabsf(d[j]));
        q[(long)(r0 + j) * WW] = (close && vv > THR_PEAKS) ? 1.0f : 0.0f;
    }
}

extern "C" void kernel_launch(void* const* d_in, const int* in_sizes, int n_in,
                              void* d_out, int out_size, void* d_ws, size_t ws_size,
                              hipStream_t stream) {
    const float* kp  = (const float*)d_in[0];
    const float* off = (const float*)d_in[1];
    float* V = (float*)d_out;            // smoothed votes -> output 0
    float* P = (float*)d_out + TOTAL;    // peaks -> output 1 (scratch earlier)
    float* W = (float*)d_ws;             // 32 MB scratch: raw votes, then rowmax

    // P region lifecycle: far-list -> row-boxsum temp -> final peaks.
    // W region lifecycle: raw votes -> row-max temp.
    hipMemsetAsync(P, 0, sizeof(int), stream);                 // far counter
    gather_votes <<<512,  512, 0, stream>>>(kp, off, W, P);    // W = raw votes
    far_scatter  <<<256,  256, 0, stream>>>(P, W);             // + far votes
    box_row      <<<8192, 256, 0, stream>>>(W, P);             // P = rowsum/D
    box_col      <<<8192, 256, 0, stream>>>(P, V);             // V = smoothed
    max_row      <<<8192, 256, 0, stream>>>(V, W);             // W = rowmax
    max_col_peaks<<<8192, 256, 0, stream>>>(W, V, P);          // P = peaks
}

// Round 5
// 392.073 us; speedup vs baseline: 1.8477x; 1.0106x over previous
//
#include <hip/hip_runtime.h>

constexpr int BB = 8;
constexpr int HH = 1024;
constexpr int WW = 1024;
constexpr int HW = HH * WW;
constexpr int TOTAL = BB * HW;

constexpr float RADIUS = 15.0f;
constexpr float THR_VOTES = 0.01f;
constexpr float THR_PEAKS = 0.2f;
// pi * 15^2 in double, rounded to f32 (matches jnp: votes / (np.pi*R*R))
constexpr float DIVISOR = 706.8583470577035f;

constexpr int TS = 128;         // gather output tile
constexpr int AP = 48;          // apron: votes with |delta|<=48 are "near"
constexpr int RG = TS + 2 * AP; // 224 input region per tile
constexpr int RGF = RG / 4;     // 56 float4 units per region row
constexpr int NF4 = RG * RGF;   // 12544 float4 units per region
constexpr int FAR_CAP = (TOTAL - 16) / 2;

// ---------------------------------------------------------------------------
// Pass 1: gather votes, float4-wide. Each block owns a 128x128 tile, scans
// its 224x224 source region in float4 units (3 vector loads per 4 pixels,
// manually 2x unrolled so 6 loads are in flight per wave -> latency hiding).
// Near votes (|delta|<=48) accumulate in the target tile's LDS; far votes
// are appended to a compact list by the SOURCE pixel's tile (exactly-once).
// ---------------------------------------------------------------------------
__device__ __forceinline__ void process4(int px0, int py, float4 kw, float4 fox,
                                         float4 foy, int tx0, int ty0, int b,
                                         float* tile, float* farbuf) {
    const float w[4]  = {kw.x, kw.y, kw.z, kw.w};
    const float ox[4] = {fox.x, fox.y, fox.z, fox.w};
    const float oy[4] = {foy.x, foy.y, foy.z, foy.w};
#pragma unroll
    for (int j = 0; j < 4; ++j) {
        const int px = px0 + j;
        // forbid FMA contraction: must match numpy's mul-then-add rounding,
        // else a .5-boundary vote lands in the adjacent cell.
        const float fx = __fadd_rn((float)px, __fmul_rn(RADIUS, ox[j]));
        const float fy = __fadd_rn((float)py, __fmul_rn(RADIUS, oy[j]));
        const int vx = (int)rintf(fx);   // round-half-even == np.round
        const int vy = (int)rintf(fy);
        if (vx < 0 || vx >= WW || vy < 0 || vy >= HH || w[j] < THR_VOTES) continue;
        const int dx = vx - px, dy = vy - py;
        if (dx >= -AP && dx <= AP && dy >= -AP && dy <= AP) {
            const int lx = vx - tx0, ly = vy - ty0;
            if (lx >= 0 && lx < TS && ly >= 0 && ly < TS)
                atomicAdd(&tile[ly * TS + lx], w[j]);
        } else if (px >= tx0 && px < tx0 + TS && py >= ty0 && py < ty0 + TS) {
            const int slot = atomicAdd((int*)farbuf, 1);
            if (slot < FAR_CAP) {
                ((int*)farbuf)[16 + 2 * slot] = b * HW + vy * WW + vx;
                farbuf[17 + 2 * slot] = w[j];
            }
        }
    }
}

__global__ __launch_bounds__(512, 4)
void gather_votes(const float* __restrict__ kp, const float* __restrict__ off,
                  float* __restrict__ vraw, float* __restrict__ farbuf) {
    __shared__ float tile[TS * TS];   // 64 KB -> 2 blocks/CU
    const int blk = blockIdx.x;       // 512 blocks = 8 batches * 64 tiles
    const int b   = blk >> 6;
    const int t   = blk & 63;
    const int ty0 = (t >> 3) * TS;
    const int tx0 = (t & 7) * TS;

    float4* tf4 = (float4*)tile;
    for (int j = threadIdx.x; j < TS * TS / 4; j += 512)
        tf4[j] = make_float4(0.f, 0.f, 0.f, 0.f);
    __syncthreads();

    const float* kpb  = kp  + (long)b * HW;
    const float* offx = off + (long)b * 2 * HW;
    const float* offy = offx + HW;

    for (int u = threadIdx.x; u < NF4; u += 1024) {
        const int uB = u + 512;
        // decode unit A
        const int rA  = u / RGF;
        const int cA  = u - rA * RGF;
        const int pyA = ty0 - AP + rA;
        const int pxA = tx0 - AP + 4 * cA;   // multiple of 4: f4 never straddles edge
        const bool okA = (pyA >= 0 && pyA < HH && pxA >= 0 && pxA <= WW - 4);
        // decode unit B
        const int rB  = uB / RGF;
        const int cB  = uB - rB * RGF;
        const int pyB = ty0 - AP + rB;
        const int pxB = tx0 - AP + 4 * cB;
        const bool okB = (uB < NF4 && pyB >= 0 && pyB < HH && pxB >= 0 && pxB <= WW - 4);

        float4 kA, xA, yA, kB, xB, yB;
        if (okA) {
            const long p = (long)pyA * WW + pxA;
            kA = *(const float4*)(kpb + p);
            xA = *(const float4*)(offx + p);
            yA = *(const float4*)(offy + p);
        }
        if (okB) {
            const long p = (long)pyB * WW + pxB;
            kB = *(const float4*)(kpb + p);
            xB = *(const float4*)(offx + p);
            yB = *(const float4*)(offy + p);
        }
        if (okA) process4(pxA, pyA, kA, xA, yA, tx0, ty0, b, tile, farbuf);
        if (okB) process4(pxB, pyB, kB, xB, yB, tx0, ty0, b, tile, farbuf);
    }
    __syncthreads();

    float* vb = vraw + (long)b * HW;
    for (int j = threadIdx.x; j < TS * TS / 4; j += 512) {
        const int r  = j / (TS / 4);
        const int c4 = j % (TS / 4);
        *(float4*)&vb[(ty0 + r) * WW + tx0 + c4 * 4] = tf4[j];
    }
}

// Pass 1b: flush the (tiny) far-vote list with global atomics.
__global__ void far_scatter(const float* __restrict__ farbuf,
                            float* __restrict__ vraw) {
    const int n = min(((const int*)farbuf)[0], FAR_CAP);
    const int stride = gridDim.x * blockDim.x;
    for (int i = blockIdx.x * blockDim.x + threadIdx.x; i < n; i += stride) {
        const int tg = ((const int*)farbuf)[16 + 2 * i];
        atomicAdd(&vraw[tg], farbuf[17 + 2 * i]);
    }
}

// ---------------------------------------------------------------------------
// Pass 2: 15x15 box-sum, separable, /DIVISOR folded into row pass.
// ---------------------------------------------------------------------------
__global__ __launch_bounds__(256)
void box_row(const float* __restrict__ in, float* __restrict__ out) {
    const long base = (long)blockIdx.x * WW;   // one image row per block
    const int c0 = threadIdx.x * 4;
    float v[20];
#pragma unroll
    for (int k = 0; k < 5; ++k) {
        const int c = c0 - 8 + 4 * k;
        float4 f = (c >= 0 && c <= WW - 4) ? *(const float4*)&in[base + c]
                                           : make_float4(0.f, 0.f, 0.f, 0.f);
        v[4 * k + 0] = f.x; v[4 * k + 1] = f.y;
        v[4 * k + 2] = f.z; v[4 * k + 3] = f.w;
    }
    float s = 0.f;
#pragma unroll
    for (int k = 1; k <= 15; ++k) s += v[k];
    float4 o;
    o.x = s / DIVISOR;
    s += v[16] - v[1];  o.y = s / DIVISOR;
    s += v[17] - v[2];  o.z = s / DIVISOR;
    s += v[18] - v[3];  o.w = s / DIVISOR;
    *(float4*)&out[base + c0] = o;
}

// 8 vertical outputs per thread (rows r0..r0+7) from 22 coalesced reads.
__global__ __launch_bounds__(256)
void box_col(const float* __restrict__ in, float* __restrict__ out) {
    const int bi = blockIdx.x;               // 4096 = 8b * 128rg * 4xg
    const int xg = bi & 3;
    const int rg = (bi >> 2) & 127;
    const int b  = bi >> 9;
    const int x  = xg * 256 + threadIdx.x;
    const int r0 = rg * 8;
    const float* p = in + (long)b * HW + x;
    float v[22];
#pragma unroll
    for (int k = 0; k < 22; ++k) {
        const int r = r0 - 7 + k;
        v[k] = (r >= 0 && r < HH) ? p[(long)r * WW] : 0.f;
    }
    float s = 0.f;
#pragma unroll
    for (int k = 0; k < 15; ++k) s += v[k];
    float* q = out + (long)b * HW + x;
    q[(long)r0 * WW] = s;
#pragma unroll
    for (int j = 1; j < 8; ++j) {
        s += v[14 + j] - v[j - 1];
        q[(long)(r0 + j) * WW] = s;
    }
}

// ---------------------------------------------------------------------------
// Pass 3: 17x17 max-pool, separable; col pass fused with the peak decision.
// ---------------------------------------------------------------------------
__global__ __launch_bounds__(256)
void max_row(const float* __restrict__ in, float* __restrict__ out) {
    const long base = (long)blockIdx.x * WW;
    const int c0 = threadIdx.x * 4;
    float v[20];
#pragma unroll
    for (int k = 0; k < 5; ++k) {
        const int c = c0 - 8 + 4 * k;
        float4 f = (c >= 0 && c <= WW - 4)
                       ? *(const float4*)&in[base + c]
                       : make_float4(-INFINITY, -INFINITY, -INFINITY, -INFINITY);
        v[4 * k + 0] = f.x; v[4 * k + 1] = f.y;
        v[4 * k + 2] = f.z; v[4 * k + 3] = f.w;
    }
    float m = v[3];
#pragma unroll
    for (int k = 4; k <= 16; ++k) m = fmaxf(m, v[k]);   // common v[3..16]
    float4 o;
    o.x = fmaxf(fmaxf(m, v[0]),  fmaxf(v[1],  v[2]));
    o.y = fmaxf(fmaxf(m, v[1]),  fmaxf(v[2],  v[17]));
    o.z = fmaxf(fmaxf(m, v[2]),  fmaxf(v[17], v[18]));
    o.w = fmaxf(fmaxf(m, v[17]), fmaxf(v[18], v[19]));
    *(float4*)&out[base + c0] = o;
}

// 8 vertical outputs per thread via suffix/prefix max over 24 rows; fused peaks.
__global__ __launch_bounds__(256)
void max_col_peaks(const float* __restrict__ rowmaxed,
                   const float* __restrict__ votes,
                   float* __restrict__ peaks) {
    const int bi = blockIdx.x;               // 4096 = 8b * 128rg * 4xg
    const int xg = bi & 3;
    const int rg = (bi >> 2) & 127;
    const int b  = bi >> 9;
    const int x  = xg * 256 + threadIdx.x;
    const int r0 = rg * 8;
    const float* p = rowmaxed + (long)b * HW + x;
    float v[24];
#pragma unroll
    for (int k = 0; k < 24; ++k) {
        const int r = r0 - 8 + k;
        v[k] = (r >= 0 && r < HH) ? p[(long)r * WW] : -INFINITY;
    }
    // output j (0..7) needs max(v[j .. j+16]). suf[j]=max(v[j..16]);
    // pre accumulates v[17..16+j].
    float suf[17];
    suf[16] = v[16];
#pragma unroll
    for (int k = 15; k >= 0; --k) suf[k] = fmaxf(v[k], suf[k + 1]);

    const float* vp = votes + (long)b * HW + x;
    float* q = peaks + (long)b * HW + x;
    float pre = -INFINITY;
#pragma unroll
    for (int j = 0; j < 8; ++j) {
        if (j > 0) pre = fmaxf(pre, v[16 + j]);
        const float d = fmaxf(suf[j], pre);
        const float vv = vp[(long)(r0 + j) * WW];
        // np.isclose(votes, dilated): |a-b| <= atol + rtol*|b|, b = dilated
        const bool close = fabsf(vv - d) <= (1e-8f + 1e-5f * fabsf(d));
        q[(long)(r0 + j) * WW] = (close && vv > THR_PEAKS) ? 1.0f : 0.0f;
    }
}

extern "C" void kernel_launch(void* const* d_in, const int* in_sizes, int n_in,
                              void* d_out, int out_size, void* d_ws, size_t ws_size,
                              hipStream_t stream) {
    const float* kp  = (const float*)d_in[0];
    const float* off = (const float*)d_in[1];
    float* V = (float*)d_out;            // smoothed votes -> output 0
    float* P = (float*)d_out + TOTAL;    // peaks -> output 1 (scratch earlier)
    float* W = (float*)d_ws;             // 32 MB scratch: raw votes, then rowmax

    // P region lifecycle: far-list -> row-boxsum temp -> final peaks.
    // W region lifecycle: raw votes -> row-max temp.
    hipMemsetAsync(P, 0, sizeof(int), stream);                 // far counter
    gather_votes <<<512,  512, 0, stream>>>(kp, off, W, P);    // W = raw votes
    far_scatter  <<<256,  256, 0, stream>>>(P, W);             // + far votes
    box_row      <<<8192, 256, 0, stream>>>(W, P);             // P = rowsum/D
    box_col      <<<4096, 256, 0, stream>>>(P, V);             // V = smoothed
    max_row      <<<8192, 256, 0, stream>>>(V, W);             // W = rowmax
    max_col_peaks<<<4096, 256, 0, stream>>>(W, V, P);          // P = peaks
}